// Round 1
// baseline (108.990 us; speedup 1.0000x reference)
//
#include <hip/hip_runtime.h>

#define HDIM 128
#define NPOS 1024
#define NCOL 512
#define LN_EPS 1e-3f

// ---------------------------------------------------------------------------
// Workspace layout (floats):
//   AcT  [128][1024]   centered seq-side A, k-major (for coalesced GEMM staging)
//   BcT  [128][512]    centered col-side B, k-major
//   p[1024] v[1024] q[512] w[512]
//   rowsum[1024]  segsum[n_seq*512]   (atomic accumulators, zeroed by k1)
//   E    [1024][512]   exp(raw)
// ---------------------------------------------------------------------------

__device__ __forceinline__ int seg_of(int i, const int* __restrict__ lens, int n_seq) {
    int cum = 0;
    for (int s = 0; s < n_seq; ++s) {
        cum += lens[s];
        if (i < cum) return s;
    }
    return n_seq - 1;
}

// ===========================================================================
// k1: per-block = 8 rows of seq (blocks 0..127) or col (blocks 128..191) side.
//  stage1: d = relu(X @ W1 + b1)     (thread t -> column h=t&127, 4 rows)
//  stage2: A = d @ Wm (+ bm on col side)
//  then center, store transposed, reduce p/q and v/w.
// Also zeroes rowsum/segsum accumulators.
// ===========================================================================
extern "C" __global__ void __launch_bounds__(256)
k1_precompute(const float* __restrict__ seq_feat, const float* __restrict__ col_feat,
              const float* __restrict__ Ws, const float* __restrict__ bsv,
              const float* __restrict__ Wc, const float* __restrict__ bcv,
              const float* __restrict__ Wm, const float* __restrict__ bmv,
              const float* __restrict__ gam, const float* __restrict__ Wo,
              float* __restrict__ AcT, float* __restrict__ BcT,
              float* __restrict__ p_arr, float* __restrict__ v_arr,
              float* __restrict__ q_arr, float* __restrict__ w_arr,
              float* __restrict__ sums, int n_seq)
{
    __shared__ float xs[8][HDIM];
    __shared__ float ds[8][HDIM];
    __shared__ float red[256];
    __shared__ float mus[8];

    const int t  = threadIdx.x;       // 0..255
    const int h  = t & (HDIM - 1);    // output column 0..127
    const int rh = t >> 7;            // row half: 0 -> rows 0..3, 1 -> rows 4..7
    const int b  = blockIdx.x;

    // zero rowsum + segsum (1024 + n_seq*512 floats) using the first blocks
    {
        int idx = b * 256 + t;
        if (idx < NPOS + n_seq * NCOL) sums[idx] = 0.f;
    }

    const bool  is_seq = (b < NPOS / 8);
    const int   i0 = (is_seq ? b : (b - NPOS / 8)) * 8;
    const float* X  = is_seq ? seq_feat : col_feat;
    const float* W1 = is_seq ? Ws : Wc;
    const float* b1 = is_seq ? bsv : bcv;

    // load 8 input rows into LDS (coalesced)
    #pragma unroll
    for (int u = 0; u < 4; ++u) {
        int fid = t + 256 * u;                 // 0..1023
        int r = fid >> 7, k = fid & (HDIM - 1);
        xs[r][k] = X[(i0 + r) * HDIM + k];
    }
    __syncthreads();

    const int rbase = rh * 4;

    // ---- stage 1: d = relu(X @ W1 + b1) ----
    {
        float bb = b1[h];
        float d0 = bb, d1 = bb, d2 = bb, d3 = bb;
        for (int k = 0; k < HDIM; k += 4) {
            float4 x0 = *(const float4*)&xs[rbase + 0][k];
            float4 x1 = *(const float4*)&xs[rbase + 1][k];
            float4 x2 = *(const float4*)&xs[rbase + 2][k];
            float4 x3 = *(const float4*)&xs[rbase + 3][k];
            float w0 = W1[(k + 0) * HDIM + h];
            float w1 = W1[(k + 1) * HDIM + h];
            float w2 = W1[(k + 2) * HDIM + h];
            float w3 = W1[(k + 3) * HDIM + h];
            d0 += x0.x * w0 + x0.y * w1 + x0.z * w2 + x0.w * w3;
            d1 += x1.x * w0 + x1.y * w1 + x1.z * w2 + x1.w * w3;
            d2 += x2.x * w0 + x2.y * w1 + x2.z * w2 + x2.w * w3;
            d3 += x3.x * w0 + x3.y * w1 + x3.z * w2 + x3.w * w3;
        }
        ds[rbase + 0][h] = fmaxf(d0, 0.f);
        ds[rbase + 1][h] = fmaxf(d1, 0.f);
        ds[rbase + 2][h] = fmaxf(d2, 0.f);
        ds[rbase + 3][h] = fmaxf(d3, 0.f);
    }
    __syncthreads();

    // ---- stage 2: A = d @ Wm (+ bm on col side) ----
    float aa0, aa1, aa2, aa3;
    {
        float bb = is_seq ? 0.f : bmv[h];
        aa0 = bb; aa1 = bb; aa2 = bb; aa3 = bb;
        for (int k = 0; k < HDIM; k += 4) {
            float4 x0 = *(const float4*)&ds[rbase + 0][k];
            float4 x1 = *(const float4*)&ds[rbase + 1][k];
            float4 x2 = *(const float4*)&ds[rbase + 2][k];
            float4 x3 = *(const float4*)&ds[rbase + 3][k];
            float w0 = Wm[(k + 0) * HDIM + h];
            float w1 = Wm[(k + 1) * HDIM + h];
            float w2 = Wm[(k + 2) * HDIM + h];
            float w3 = Wm[(k + 3) * HDIM + h];
            aa0 += x0.x * w0 + x0.y * w1 + x0.z * w2 + x0.w * w3;
            aa1 += x1.x * w0 + x1.y * w1 + x1.z * w2 + x1.w * w3;
            aa2 += x2.x * w0 + x2.y * w1 + x2.z * w2 + x2.w * w3;
            aa3 += x3.x * w0 + x3.y * w1 + x3.z * w2 + x3.w * w3;
        }
    }

    // ---- reduction round 1: row means ----
    xs[rbase + 0][h] = aa0;
    xs[rbase + 1][h] = aa1;
    xs[rbase + 2][h] = aa2;
    xs[rbase + 3][h] = aa3;
    __syncthreads();
    {
        int r = t >> 5, l = t & 31;
        red[t] = xs[r][l] + xs[r][l + 32] + xs[r][l + 64] + xs[r][l + 96];
    }
    __syncthreads();
    if (t < 8) {
        float s = 0.f;
        #pragma unroll
        for (int m = 0; m < 32; ++m) s += red[t * 32 + m];
        mus[t] = s * (1.f / HDIM);
    }
    __syncthreads();

    const float gw = gam[h] * Wo[h];
    float a0 = aa0 - mus[rbase + 0];
    float a1 = aa1 - mus[rbase + 1];
    float a2 = aa2 - mus[rbase + 2];
    float a3 = aa3 - mus[rbase + 3];

    // store centered values transposed (k-major) for k2's coalesced staging
    {
        float4 st = make_float4(a0, a1, a2, a3);
        if (is_seq) *(float4*)&AcT[h * NPOS + i0 + rbase] = st;
        else        *(float4*)&BcT[h * NCOL + i0 + rbase] = st;
    }

    // ---- reduction round 2: p = dot(a, gamma*Wo) ----
    xs[rbase + 0][h] = a0 * gw;
    xs[rbase + 1][h] = a1 * gw;
    xs[rbase + 2][h] = a2 * gw;
    xs[rbase + 3][h] = a3 * gw;
    __syncthreads();
    {
        int r = t >> 5, l = t & 31;
        red[t] = xs[r][l] + xs[r][l + 32] + xs[r][l + 64] + xs[r][l + 96];
    }
    __syncthreads();
    if (t < 8) {
        float s = 0.f;
        #pragma unroll
        for (int m = 0; m < 32; ++m) s += red[t * 32 + m];
        (is_seq ? p_arr : q_arr)[i0 + t] = s;
    }
    __syncthreads();

    // ---- reduction round 3: v = mean(a^2) ----
    xs[rbase + 0][h] = a0 * a0;
    xs[rbase + 1][h] = a1 * a1;
    xs[rbase + 2][h] = a2 * a2;
    xs[rbase + 3][h] = a3 * a3;
    __syncthreads();
    {
        int r = t >> 5, l = t & 31;
        red[t] = xs[r][l] + xs[r][l + 32] + xs[r][l + 64] + xs[r][l + 96];
    }
    __syncthreads();
    if (t < 8) {
        float s = 0.f;
        #pragma unroll
        for (int m = 0; m < 32; ++m) s += red[t * 32 + m];
        (is_seq ? v_arr : w_arr)[i0 + t] = s * (1.f / HDIM);
    }
}

// ===========================================================================
// k2: tiled fp32 GEMM  dot(a_i, b_j)  over K=128, fused with exp-epilogue.
// Tile 32 rows x 64 cols, 256 threads, each thread 2x4 outputs.
// Accumulates rowsum (per-row over all cols) and segsum (per-seg,col) via
// one LDS block-reduce + atomicAdd per row / per col.
// ===========================================================================
#define AS_STR 36
#define BS_STR 68

extern "C" __global__ void __launch_bounds__(256)
k2_gemm(const float* __restrict__ AcT, const float* __restrict__ BcT,
        const float* __restrict__ p_arr, const float* __restrict__ v_arr,
        const float* __restrict__ q_arr, const float* __restrict__ w_arr,
        const int* __restrict__ lens, int n_seq,
        float* __restrict__ E, float* __restrict__ rowsum, float* __restrict__ segsum)
{
    __shared__ float As[128 * AS_STR];   // [k][m], m-stride 36
    __shared__ float Bs[128 * BS_STR];   // [k][n], n-stride 68
    __shared__ float redr[512];          // [row32][tc16]
    __shared__ float redc[1024];         // [col64][tr16]

    const int t  = threadIdx.x;
    const int tc = t & 15;    // col group (4 cols)
    const int tr = t >> 4;    // row group (2 rows), 0..15
    const int i0 = blockIdx.x * 32;
    const int j0 = blockIdx.y * 64;

    // stage A tile: 128k x 32m = 1024 float4s
    #pragma unroll
    for (int u = 0; u < 4; ++u) {
        int fid = t + 256 * u;
        int k = fid >> 3, m4 = fid & 7;
        float4 g = *(const float4*)&AcT[k * NPOS + i0 + 4 * m4];
        *(float4*)&As[k * AS_STR + 4 * m4] = g;
    }
    // stage B tile: 128k x 64n = 2048 float4s
    #pragma unroll
    for (int u = 0; u < 8; ++u) {
        int fid = t + 256 * u;
        int k = fid >> 4, n4 = fid & 15;
        float4 g = *(const float4*)&BcT[k * NCOL + j0 + 4 * n4];
        *(float4*)&Bs[k * BS_STR + 4 * n4] = g;
    }
    __syncthreads();

    float acc00 = 0.f, acc01 = 0.f, acc02 = 0.f, acc03 = 0.f;
    float acc10 = 0.f, acc11 = 0.f, acc12 = 0.f, acc13 = 0.f;
    #pragma unroll 4
    for (int k = 0; k < 128; ++k) {
        float2 a2 = *(const float2*)&As[k * AS_STR + 2 * tr];
        float4 b4 = *(const float4*)&Bs[k * BS_STR + 4 * tc];
        acc00 += a2.x * b4.x; acc01 += a2.x * b4.y; acc02 += a2.x * b4.z; acc03 += a2.x * b4.w;
        acc10 += a2.y * b4.x; acc11 += a2.y * b4.y; acc12 += a2.y * b4.z; acc13 += a2.y * b4.w;
    }

    // ---- epilogue: E = exp((p+q) * rsqrt(v + w + 2/H*dot + eps)) ----
    const int jj = j0 + 4 * tc;
    float4 q4 = *(const float4*)&q_arr[jj];
    float4 w4 = *(const float4*)&w_arr[jj];

    float e[2][4];
    float rs[2];
    #pragma unroll
    for (int mm = 0; mm < 2; ++mm) {
        const int i = i0 + 2 * tr + mm;
        const float pi = p_arr[i];
        const float vi = v_arr[i];
        float d0 = (mm == 0) ? acc00 : acc10;
        float d1 = (mm == 0) ? acc01 : acc11;
        float d2 = (mm == 0) ? acc02 : acc12;
        float d3 = (mm == 0) ? acc03 : acc13;
        e[mm][0] = __expf((pi + q4.x) * rsqrtf(vi + w4.x + d0 * (2.f / HDIM) + LN_EPS));
        e[mm][1] = __expf((pi + q4.y) * rsqrtf(vi + w4.y + d1 * (2.f / HDIM) + LN_EPS));
        e[mm][2] = __expf((pi + q4.z) * rsqrtf(vi + w4.z + d2 * (2.f / HDIM) + LN_EPS));
        e[mm][3] = __expf((pi + q4.w) * rsqrtf(vi + w4.w + d3 * (2.f / HDIM) + LN_EPS));
        rs[mm] = e[mm][0] + e[mm][1] + e[mm][2] + e[mm][3];
        float4 st = make_float4(e[mm][0], e[mm][1], e[mm][2], e[mm][3]);
        *(float4*)&E[i * NCOL + jj] = st;
    }

    // block-level partial reductions
    redr[(2 * tr + 0) * 16 + tc] = rs[0];
    redr[(2 * tr + 1) * 16 + tc] = rs[1];
    #pragma unroll
    for (int u = 0; u < 4; ++u)
        redc[(4 * tc + u) * 16 + tr] = e[0][u] + e[1][u];

    const int seg_lo = seg_of(i0, lens, n_seq);
    const int seg_hi = seg_of(i0 + 31, lens, n_seq);
    __syncthreads();

    if (t < 32) {
        float s = 0.f;
        #pragma unroll
        for (int m = 0; m < 16; ++m) s += redr[t * 16 + m];
        atomicAdd(&rowsum[i0 + t], s);
    } else if (t < 96 && seg_lo == seg_hi) {
        int c = t - 32;
        float s = 0.f;
        #pragma unroll
        for (int m = 0; m < 16; ++m) s += redc[c * 16 + m];
        atomicAdd(&segsum[seg_lo * NCOL + j0 + c], s);
    }
    if (seg_lo != seg_hi) {
        // rare generic path: tile crosses a segment boundary
        #pragma unroll
        for (int mm = 0; mm < 2; ++mm) {
            const int i = i0 + 2 * tr + mm;
            const int sg = seg_of(i, lens, n_seq);
            #pragma unroll
            for (int u = 0; u < 4; ++u)
                atomicAdd(&segsum[sg * NCOL + jj + u], e[mm][u]);
        }
    }
}

// ===========================================================================
// k3: out = M_c + M_s - M_c*M_s,  M_c = E/rowsum[i], M_s = E/segsum[seg(i)][j]
// ===========================================================================
extern "C" __global__ void __launch_bounds__(256)
k3_final(const float* __restrict__ E, const float* __restrict__ rowsum,
         const float* __restrict__ segsum, const int* __restrict__ lens, int n_seq,
         float* __restrict__ out)
{
    const int gid = blockIdx.x * 256 + threadIdx.x;   // 131072 float4 groups
    const int i = gid >> 7;
    const int j = (gid & 127) * 4;

    float4 e4 = *(const float4*)&E[i * NCOL + j];
    const float invr = 1.f / rowsum[i];
    const int sg = seg_of(i, lens, n_seq);
    float4 s4 = *(const float4*)&segsum[sg * NCOL + j];

    float4 o;
    {
        float mc = e4.x * invr, ms = e4.x / s4.x; o.x = mc + ms - mc * ms;
    }
    {
        float mc = e4.y * invr, ms = e4.y / s4.y; o.y = mc + ms - mc * ms;
    }
    {
        float mc = e4.z * invr, ms = e4.z / s4.z; o.z = mc + ms - mc * ms;
    }
    {
        float mc = e4.w * invr, ms = e4.w / s4.w; o.w = mc + ms - mc * ms;
    }
    *(float4*)&out[i * NCOL + j] = o;
}

// ===========================================================================
extern "C" void kernel_launch(void* const* d_in, const int* in_sizes, int n_in,
                              void* d_out, int out_size, void* d_ws, size_t ws_size,
                              hipStream_t stream) {
    const float* seq_feat = (const float*)d_in[0];
    const float* col_feat = (const float*)d_in[1];
    const int*   lens     = (const int*)d_in[2];
    const float* Ws   = (const float*)d_in[3];
    const float* bs   = (const float*)d_in[4];
    const float* Wc   = (const float*)d_in[5];
    const float* bc   = (const float*)d_in[6];
    const float* Wm   = (const float*)d_in[7];
    const float* bm   = (const float*)d_in[8];
    const float* gam  = (const float*)d_in[9];
    // d_in[10] = beta, d_in[12] = bo: provably cancel in both normalizations
    const float* Wo   = (const float*)d_in[11];
    float* out = (float*)d_out;
    const int n_seq = in_sizes[2];

    float* ws    = (float*)d_ws;
    float* AcT   = ws;                    // 128*1024
    float* BcT   = AcT + HDIM * NPOS;     // 128*512
    float* p     = BcT + HDIM * NCOL;     // 1024
    float* v     = p + NPOS;              // 1024
    float* q     = v + NPOS;              // 512
    float* w     = q + NCOL;              // 512
    float* sums  = w + NCOL;              // rowsum 1024 + segsum n_seq*512
    float* rowsum = sums;
    float* segsum = sums + NPOS;
    float* E     = segsum + n_seq * NCOL; // 1024*512

    hipLaunchKernelGGL(k1_precompute, dim3(NPOS / 8 + NCOL / 8), dim3(256), 0, stream,
                       seq_feat, col_feat, Ws, bs, Wc, bc, Wm, bm, gam, Wo,
                       AcT, BcT, p, v, q, w, sums, n_seq);
    hipLaunchKernelGGL(k2_gemm, dim3(NPOS / 32, NCOL / 64), dim3(256), 0, stream,
                       AcT, BcT, p, v, q, w, lens, n_seq, E, rowsum, segsum);
    hipLaunchKernelGGL(k3_final, dim3((NPOS * NCOL / 4) / 256), dim3(256), 0, stream,
                       E, rowsum, segsum, lens, n_seq, out);
}

// Round 2
// 100.926 us; speedup vs baseline: 1.0799x; 1.0799x over previous
//
#include <hip/hip_runtime.h>

#define HDIM 128
#define NPOS 1024
#define NCOL 512
#define LN_EPS 1e-3f

// ---------------------------------------------------------------------------
// Workspace layout (floats):
//   AcT  [128][1024]  centered seq-side A, k-major
//   BcT  [128][512]   centered col-side B, k-major
//   p[1024] v[1024] q[512] w[512]
//   rowsum[1024]  segsum[n_seq*512]  (atomics, zeroed by k1)
//   E    [1024][512]
//   segid[1024] (int)  per-row segment id LUT (filled by k1)
// ---------------------------------------------------------------------------

__device__ __forceinline__ int seg_of(int i, const int* __restrict__ lens, int n_seq) {
    int cum = 0;
    for (int s = 0; s < n_seq; ++s) {
        cum += lens[s];
        if (i < cum) return s;
    }
    return n_seq - 1;
}

// ===========================================================================
// k1: 384 blocks x 512 threads. Block b: 4 rows of seq (b<256) or col side.
// Thread (r = t>>7, h = t&127) computes one element of both GEMM stages.
// W loads from global (L2-resident), unroll 8 -> 32 loads in flight.
// Shuffle-based reductions for mean / p / v. LDS-transposed store of AcT/BcT.
// Also zeroes rowsum/segsum and fills segid LUT.
// ===========================================================================
extern "C" __global__ void __launch_bounds__(512)
k1_precompute(const float* __restrict__ seq_feat, const float* __restrict__ col_feat,
              const float* __restrict__ Ws, const float* __restrict__ bsv,
              const float* __restrict__ Wc, const float* __restrict__ bcv,
              const float* __restrict__ Wm, const float* __restrict__ bmv,
              const float* __restrict__ gam, const float* __restrict__ Wo,
              const int* __restrict__ lens, int n_seq,
              float* __restrict__ AcT, float* __restrict__ BcT,
              float* __restrict__ p_arr, float* __restrict__ v_arr,
              float* __restrict__ q_arr, float* __restrict__ w_arr,
              float* __restrict__ sums, int* __restrict__ segid)
{
    __shared__ float xs[4][HDIM];
    __shared__ float ds_[4][HDIM];
    __shared__ float partm[8], partp[8], partv[8], mus[4];

    const int t    = threadIdx.x;
    const int b    = blockIdx.x;
    const int h    = t & 127;
    const int r    = t >> 7;       // row 0..3 (uniform per wave)
    const int wv   = t >> 6;       // wave 0..7
    const int lane = t & 63;

    // housekeeping: zero accumulators + fill segid LUT
    {
        const int nsums = NPOS + n_seq * NCOL;
        int idx = b * 512 + t;
        if (idx < nsums) sums[idx] = 0.f;
        int idx2 = idx - nsums;
        if (idx2 >= 0 && idx2 < NPOS) segid[idx2] = seg_of(idx2, lens, n_seq);
    }

    const bool  is_seq = (b < NPOS / 4);
    const int   i0 = (is_seq ? b : (b - NPOS / 4)) * 4;
    const float* X  = is_seq ? seq_feat : col_feat;
    const float* W1 = is_seq ? Ws : Wc;
    const float* b1 = is_seq ? bsv : bcv;

    // stage 4 input rows into LDS (128 threads x float4)
    if (t < 128) {
        int rr = t >> 5, k4 = (t & 31) * 4;
        *(float4*)&xs[rr][k4] = *(const float4*)&X[(i0 + rr) * HDIM + k4];
    }
    __syncthreads();

    // ---- stage 1: d = relu(x_r . W1[:,h] + b1[h]) ----
    float d;
    {
        float a0 = 0.f, a1 = 0.f, a2 = 0.f, a3 = 0.f;
        #pragma unroll 8
        for (int k = 0; k < HDIM; k += 4) {
            float4 x = *(const float4*)&xs[r][k];
            float w0 = W1[(k + 0) * HDIM + h];
            float w1 = W1[(k + 1) * HDIM + h];
            float w2 = W1[(k + 2) * HDIM + h];
            float w3 = W1[(k + 3) * HDIM + h];
            a0 += x.x * w0; a1 += x.y * w1; a2 += x.z * w2; a3 += x.w * w3;
        }
        d = fmaxf(b1[h] + ((a0 + a1) + (a2 + a3)), 0.f);
    }
    ds_[r][h] = d;
    __syncthreads();

    // ---- stage 2: aa = d_r . Wm[:,h] (+ bm on col side) ----
    float aa;
    {
        float a0 = 0.f, a1 = 0.f, a2 = 0.f, a3 = 0.f;
        #pragma unroll 8
        for (int k = 0; k < HDIM; k += 4) {
            float4 x = *(const float4*)&ds_[r][k];
            float w0 = Wm[(k + 0) * HDIM + h];
            float w1 = Wm[(k + 1) * HDIM + h];
            float w2 = Wm[(k + 2) * HDIM + h];
            float w3 = Wm[(k + 3) * HDIM + h];
            a0 += x.x * w0; a1 += x.y * w1; a2 += x.z * w2; a3 += x.w * w3;
        }
        aa = (is_seq ? 0.f : bmv[h]) + ((a0 + a1) + (a2 + a3));
    }

    // ---- row mean (butterfly over the 2 waves holding row r) ----
    {
        float s = aa;
        #pragma unroll
        for (int off = 32; off; off >>= 1) s += __shfl_xor(s, off, 64);
        if (lane == 0) partm[wv] = s;
    }
    __syncthreads();
    if (t < 4) mus[t] = (partm[2 * t] + partm[2 * t + 1]) * (1.f / HDIM);
    __syncthreads();

    const float a  = aa - mus[r];
    const float gw = gam[h] * Wo[h];

    // ---- p = dot(a, gamma*Wo), v = mean(a^2) ----
    {
        float sp = a * gw, sv = a * a;
        #pragma unroll
        for (int off = 32; off; off >>= 1) {
            sp += __shfl_xor(sp, off, 64);
            sv += __shfl_xor(sv, off, 64);
        }
        if (lane == 0) { partp[wv] = sp; partv[wv] = sv; }
    }
    xs[r][h] = a;   // reuse xs for transpose staging
    __syncthreads();
    if (t < 4) {
        (is_seq ? p_arr : q_arr)[i0 + t] = partp[2 * t] + partp[2 * t + 1];
        (is_seq ? v_arr : w_arr)[i0 + t] = (partv[2 * t] + partv[2 * t + 1]) * (1.f / HDIM);
    }
    // transposed (k-major) store: row h gets the 4 centered values
    if (t < 128) {
        float4 st = make_float4(xs[0][t], xs[1][t], xs[2][t], xs[3][t]);
        if (is_seq) *(float4*)&AcT[t * NPOS + i0] = st;
        else        *(float4*)&BcT[t * NCOL + i0] = st;
    }
}

// ===========================================================================
// k2: tiled fp32 GEMM dot(a_i,b_j), K=128, fused exp-epilogue + sum atomics.
// Tile 32 rows x 64 cols, 512 threads: waves 0-3 take k<64, waves 4-7 k>=64,
// combine partials through LDS. LDS <=64KB via union reuse.
// ===========================================================================
#define AS_STR 36
#define BS_STR 68

union K2Smem {
    struct { float As[128 * AS_STR]; float Bs[128 * BS_STR]; } s;
    struct { float comb[8 * 256]; float redr[512]; float redc[1024]; } r;
};

extern "C" __global__ void __launch_bounds__(512)
k2_gemm(const float* __restrict__ AcT, const float* __restrict__ BcT,
        const float* __restrict__ p_arr, const float* __restrict__ v_arr,
        const float* __restrict__ q_arr, const float* __restrict__ w_arr,
        const int* __restrict__ segid, int n_seq,
        float* __restrict__ E, float* __restrict__ rowsum, float* __restrict__ segsum)
{
    __shared__ K2Smem sm;

    const int t  = threadIdx.x;
    const int tt = t & 255;
    const int tc = tt & 15;      // col group (4 cols)
    const int tr = tt >> 4;      // row group (2 rows)
    const int kbase = (t >> 8) * 64;
    const int i0 = blockIdx.x * 32;
    const int j0 = blockIdx.y * 64;

    // stage A tile (128k x 32m) and B tile (128k x 64n), all 512 threads
    #pragma unroll
    for (int u = 0; u < 2; ++u) {
        int fid = t + 512 * u;                  // 0..1023
        int k = fid >> 3, m4 = fid & 7;
        *(float4*)&sm.s.As[k * AS_STR + 4 * m4] = *(const float4*)&AcT[k * NPOS + i0 + 4 * m4];
    }
    #pragma unroll
    for (int u = 0; u < 4; ++u) {
        int fid = t + 512 * u;                  // 0..2047
        int k = fid >> 4, n4 = fid & 15;
        *(float4*)&sm.s.Bs[k * BS_STR + 4 * n4] = *(const float4*)&BcT[k * NCOL + j0 + 4 * n4];
    }
    __syncthreads();

    float acc[8] = {0.f, 0.f, 0.f, 0.f, 0.f, 0.f, 0.f, 0.f};
    #pragma unroll 4
    for (int k = kbase; k < kbase + 64; ++k) {
        float2 a2 = *(const float2*)&sm.s.As[k * AS_STR + 2 * tr];
        float4 b4 = *(const float4*)&sm.s.Bs[k * BS_STR + 4 * tc];
        acc[0] += a2.x * b4.x; acc[1] += a2.x * b4.y; acc[2] += a2.x * b4.z; acc[3] += a2.x * b4.w;
        acc[4] += a2.y * b4.x; acc[5] += a2.y * b4.y; acc[6] += a2.y * b4.z; acc[7] += a2.y * b4.w;
    }

    const int seg_lo = segid[i0];
    const int seg_hi = segid[i0 + 31];
    __syncthreads();   // all waves done with As/Bs; union region reusable

    if (t >= 256) {
        #pragma unroll
        for (int j = 0; j < 8; ++j) sm.r.comb[j * 256 + tt] = acc[j];
    }
    __syncthreads();

    float e[2][4];
    if (t < 256) {
        #pragma unroll
        for (int j = 0; j < 8; ++j) acc[j] += sm.r.comb[j * 256 + tt];

        const int jj = j0 + 4 * tc;
        float4 q4 = *(const float4*)&q_arr[jj];
        float4 w4 = *(const float4*)&w_arr[jj];
        float rs[2];
        #pragma unroll
        for (int mm = 0; mm < 2; ++mm) {
            const int i = i0 + 2 * tr + mm;
            const float pi = p_arr[i];
            const float vi = v_arr[i];
            e[mm][0] = __expf((pi + q4.x) * rsqrtf(vi + w4.x + acc[4*mm+0] * (2.f/HDIM) + LN_EPS));
            e[mm][1] = __expf((pi + q4.y) * rsqrtf(vi + w4.y + acc[4*mm+1] * (2.f/HDIM) + LN_EPS));
            e[mm][2] = __expf((pi + q4.z) * rsqrtf(vi + w4.z + acc[4*mm+2] * (2.f/HDIM) + LN_EPS));
            e[mm][3] = __expf((pi + q4.w) * rsqrtf(vi + w4.w + acc[4*mm+3] * (2.f/HDIM) + LN_EPS));
            rs[mm] = e[mm][0] + e[mm][1] + e[mm][2] + e[mm][3];
            *(float4*)&E[i * NCOL + jj] = make_float4(e[mm][0], e[mm][1], e[mm][2], e[mm][3]);
        }
        sm.r.redr[(2 * tr + 0) * 16 + tc] = rs[0];
        sm.r.redr[(2 * tr + 1) * 16 + tc] = rs[1];
        #pragma unroll
        for (int u = 0; u < 4; ++u)
            sm.r.redc[(4 * tc + u) * 16 + tr] = e[0][u] + e[1][u];
    }
    __syncthreads();

    if (t < 32) {
        float s = 0.f;
        #pragma unroll
        for (int m = 0; m < 16; ++m) s += sm.r.redr[t * 16 + m];
        atomicAdd(&rowsum[i0 + t], s);
    } else if (t >= 32 && t < 96 && seg_lo == seg_hi) {
        int c = t - 32;
        float s = 0.f;
        #pragma unroll
        for (int m = 0; m < 16; ++m) s += sm.r.redc[c * 16 + m];
        atomicAdd(&segsum[seg_lo * NCOL + j0 + c], s);
    }
    if (seg_lo != seg_hi && t < 256) {
        // generic path: tile crosses a segment boundary (not hit for 8x128)
        #pragma unroll
        for (int mm = 0; mm < 2; ++mm) {
            const int i = i0 + 2 * tr + mm;
            const int sg = segid[i];
            #pragma unroll
            for (int u = 0; u < 4; ++u)
                atomicAdd(&segsum[sg * NCOL + j0 + 4 * tc + u], e[mm][u]);
        }
    }
}

// ===========================================================================
// k3: out = M_c + M_s - M_c*M_s
// ===========================================================================
extern "C" __global__ void __launch_bounds__(256)
k3_final(const float* __restrict__ E, const float* __restrict__ rowsum,
         const float* __restrict__ segsum, const int* __restrict__ segid,
         float* __restrict__ out)
{
    const int gid = blockIdx.x * 256 + threadIdx.x;   // 131072 float4 groups
    const int i = gid >> 7;
    const int j = (gid & 127) * 4;

    float4 e4 = *(const float4*)&E[i * NCOL + j];
    const float invr = 1.f / rowsum[i];
    const int sg = segid[i];
    float4 s4 = *(const float4*)&segsum[sg * NCOL + j];

    float4 o;
    { float mc = e4.x * invr, ms = e4.x / s4.x; o.x = mc + ms - mc * ms; }
    { float mc = e4.y * invr, ms = e4.y / s4.y; o.y = mc + ms - mc * ms; }
    { float mc = e4.z * invr, ms = e4.z / s4.z; o.z = mc + ms - mc * ms; }
    { float mc = e4.w * invr, ms = e4.w / s4.w; o.w = mc + ms - mc * ms; }
    *(float4*)&out[i * NCOL + j] = o;
}

// ===========================================================================
extern "C" void kernel_launch(void* const* d_in, const int* in_sizes, int n_in,
                              void* d_out, int out_size, void* d_ws, size_t ws_size,
                              hipStream_t stream) {
    const float* seq_feat = (const float*)d_in[0];
    const float* col_feat = (const float*)d_in[1];
    const int*   lens     = (const int*)d_in[2];
    const float* Ws   = (const float*)d_in[3];
    const float* bs   = (const float*)d_in[4];
    const float* Wc   = (const float*)d_in[5];
    const float* bc   = (const float*)d_in[6];
    const float* Wm   = (const float*)d_in[7];
    const float* bm   = (const float*)d_in[8];
    const float* gam  = (const float*)d_in[9];
    // d_in[10] = beta, d_in[12] = bo: cancel in both normalizations
    const float* Wo   = (const float*)d_in[11];
    float* out = (float*)d_out;
    const int n_seq = in_sizes[2];

    float* ws     = (float*)d_ws;
    float* AcT    = ws;                    // 128*1024
    float* BcT    = AcT + HDIM * NPOS;     // 128*512
    float* p      = BcT + HDIM * NCOL;     // 1024
    float* v      = p + NPOS;              // 1024
    float* q      = v + NPOS;              // 512
    float* w      = q + NCOL;              // 512
    float* sums   = w + NCOL;              // rowsum 1024 + segsum n_seq*512
    float* rowsum = sums;
    float* segsum = sums + NPOS;
    float* E      = segsum + n_seq * NCOL; // 1024*512
    int*   segid  = (int*)(E + NPOS * NCOL); // 1024 ints

    hipLaunchKernelGGL(k1_precompute, dim3(NPOS / 4 + NCOL / 4), dim3(512), 0, stream,
                       seq_feat, col_feat, Ws, bs, Wc, bc, Wm, bm, gam, Wo,
                       lens, n_seq, AcT, BcT, p, v, q, w, sums, segid);
    hipLaunchKernelGGL(k2_gemm, dim3(NPOS / 32, NCOL / 64), dim3(512), 0, stream,
                       AcT, BcT, p, v, q, w, segid, n_seq, E, rowsum, segsum);
    hipLaunchKernelGGL(k3_final, dim3((NPOS * NCOL / 4) / 256), dim3(256), 0, stream,
                       E, rowsum, segsum, segid, out);
}